// Round 2
// baseline (351.881 us; speedup 1.0000x reference)
//
#include <hip/hip_runtime.h>

// Problem constants (fixed by setup_inputs: B=128, S=524288, target_len=256).
// L = S / target_len = 2048 floats per segment; segments tile flat memory.
#define SEG_LEN 2048
#define GAPS_INV (1.0f / 2047.0f)

// One wave (64 lanes) per segment; 4 segments per 256-thread block.
// Iteration j: lane i loads the float4 at segment offset j*256 + i*4 floats —
// each wave VMEM instruction is a fully-used contiguous 1 KiB access (perfect
// coalescing). Boundary gaps between lanes/iterations come from shuffles:
// no redundant global loads, no LDS, no __syncthreads.
__global__ __launch_bounds__(256)
void seg_change_strength_kernel(const float* __restrict__ x,
                                float* __restrict__ out) {
    const int lane = threadIdx.x & 63;
    const int waveInBlock = threadIdx.x >> 6;               // 0..3
    const int seg = (blockIdx.x << 2) + waveInBlock;        // segment id
    const float* base = x + (long long)seg * SEG_LEN + lane * 4;

    float s = 0.0f;
    float carry = 0.0f;  // broadcast of previous iteration's lane-63 v.w
    #pragma unroll
    for (int j = 0; j < 8; ++j) {
        const float4 v = *(const float4*)(base + j * 256);
        // 3 internal gaps of this float4 (gaps 4i, 4i+1, 4i+2 of this chunk)
        float sl = fabsf(v.y - v.x) + fabsf(v.z - v.y) + fabsf(v.w - v.z);
        // gap 4i+3: next lane's first element (lanes 0..62)
        const float nx = __shfl_down(v.x, 1, 64);
        if (lane < 63) sl += fabsf(nx - v.w);
        // cross-iteration gap: prev iter's element 255 -> this iter's element 0
        if (j > 0 && lane == 0) sl += fabsf(v.x - carry);
        s += sl;
        carry = __shfl(v.w, 63, 64);
    }

    // Wave-64 butterfly reduction; lane 0 holds the segment sum.
    #pragma unroll
    for (int off = 32; off > 0; off >>= 1)
        s += __shfl_down(s, off, 64);
    if (lane == 0) out[seg] = s * GAPS_INV;
}

extern "C" void kernel_launch(void* const* d_in, const int* in_sizes, int n_in,
                              void* d_out, int out_size, void* d_ws, size_t ws_size,
                              hipStream_t stream) {
    const float* x = (const float*)d_in[0];
    float* out = (float*)d_out;
    const int n = in_sizes[0];              // B * S = 67108864
    const int nseg = n / SEG_LEN;           // 32768 segments = out_size
    seg_change_strength_kernel<<<nseg / 4, 256, 0, stream>>>(x, out);
}